// Round 5
// baseline (177.557 us; speedup 1.0000x reference)
//
#include <hip/hip_runtime.h>
#include <hip/hip_bf16.h>

#define DDIM 1024
#define RREG 36
#define TTOK 64
#define KPAD 48     // attn rows padded 36->48, rows [36,48) zero
#define SLOTSTR 49  // pdots per-t stride in dwords (49: kq-lanes land in distinct banks)

typedef __attribute__((ext_vector_type(4))) float f32x4;
typedef __attribute__((ext_vector_type(8))) short bf16x8;

__device__ __forceinline__ float sq4(float4 v) {
  return v.x * v.x + v.y * v.y + v.z * v.z + v.w * v.w;
}

__device__ __forceinline__ bf16x8 cvt8(float4 a, float4 b) {
  union { bf16x8 v; __hip_bfloat162 h[4]; } u;
  u.h[0] = __float22bfloat162_rn(make_float2(a.x, a.y));
  u.h[1] = __float22bfloat162_rn(make_float2(a.z, a.w));
  u.h[2] = __float22bfloat162_rn(make_float2(b.x, b.y));
  u.h[3] = __float22bfloat162_rn(make_float2(b.z, b.w));
  return u.v;
}

__device__ __forceinline__ bf16x8 pack8(const float* v) {
  union { bf16x8 x; __hip_bfloat162 h[4]; } u;
#pragma unroll
  for (int i = 0; i < 4; ++i)
    u.h[i] = __float22bfloat162_rn(make_float2(v[2 * i], v[2 * i + 1]));
  return u.x;
}

__device__ __forceinline__ unsigned short f2bf(float x) {
  unsigned int u = __float_as_uint(x);
  u += 0x7fffu + ((u >> 16) & 1u);
  return (unsigned short)(u >> 16);
}

// ---------------- Kernel 1: dots + norms + softmax -> attn^T bf16 ----------------
// grid = B (ONE block per batch: cap and img each REQUESTED exactly once --
// the ~7-9 B/cyc/CU request-throughput law says duplication, not latency or
// barriers, set the previous 50us). block = 512 = 8 waves; wave w owns
// K-slice [w*128,(w+1)*128) and computes the FULL 64x48 dot tile for it:
// 12 f32x4 accs, global-direct fragment gathers (no LDS in the K-loop).
// Split-K combine via 50 KB LDS scratch in 2 rounds, then exact fp32 norms
// + softmax. Requested/CU = 448 KB vs R4's 832 KB -> predicted ~2x.
__global__ __launch_bounds__(512) void scan_attn(
    const float* __restrict__ img, const float* __restrict__ cap,
    unsigned short* __restrict__ attnw) {
  __shared__ __align__(16) unsigned char smem[53760];
  float* pdots = (float*)smem;             // 4 slots x [64][SLOTSTR] f32 = 50176 B
  float* snc_p = (float*)(smem + 50176);   // [8][64] f32 cap-norm^2 partials
  float* sni_p = (float*)(smem + 52224);   // [8][48] f32 img-norm^2 partials

  const int tid  = threadIdx.x;
  const int lane = tid & 63;
  const int w    = tid >> 6;   // K-slice 0..7
  const int fm   = lane & 15;
  const int kq   = lane >> 4;
  const int b    = blockIdx.x;

  const float* capb = cap + (size_t)b * TTOK * DDIM;
  const float* imgb = img + (size_t)b * RREG * DDIM;

  const float* capk = capb + w * 128 + kq * 8;
  const float* imgk = imgb + w * 128 + kq * 8;

  f32x4 acc[4][3];
#pragma unroll
  for (int tt = 0; tt < 4; ++tt)
#pragma unroll
    for (int rt = 0; rt < 3; ++rt) acc[tt][rt] = (f32x4){0.f, 0.f, 0.f, 0.f};
  float cnp[4] = {0.f, 0.f, 0.f, 0.f};
  float inp[3] = {0.f, 0.f, 0.f};

  const int  r2  = 32 + fm;           // rt=2 row
  const bool r2v = (r2 < RREG);

#pragma unroll
  for (int ks = 0; ks < 4; ++ks) {
    const int ko = ks * 32;
    // A: cap rows tt*16+fm, 32B/lane (2x float4), k-contiguous
    float4 a0[4], a1[4];
#pragma unroll
    for (int tt = 0; tt < 4; ++tt) {
      const float* p = capk + (tt * 16 + fm) * DDIM + ko;
      a0[tt] = *(const float4*)p;
      a1[tt] = *(const float4*)(p + 4);
    }
    // B: img rows rt*16+fm (rt=2 partially invalid -> clamp to row0, zero)
    float4 b0[3], b1[3];
#pragma unroll
    for (int rt = 0; rt < 2; ++rt) {
      const float* p = imgk + (rt * 16 + fm) * DDIM + ko;
      b0[rt] = *(const float4*)p;
      b1[rt] = *(const float4*)(p + 4);
    }
    {
      const float* p = imgk + (r2v ? r2 : 0) * DDIM + ko;
      float4 t0 = *(const float4*)p;
      float4 t1 = *(const float4*)(p + 4);
      if (!r2v) { t0 = make_float4(0.f, 0.f, 0.f, 0.f); t1 = t0; }
      b0[2] = t0; b1[2] = t1;
    }
    // exact fp32 norm partials (pre-conversion)
#pragma unroll
    for (int tt = 0; tt < 4; ++tt) cnp[tt] += sq4(a0[tt]) + sq4(a1[tt]);
#pragma unroll
    for (int rt = 0; rt < 3; ++rt) inp[rt] += sq4(b0[rt]) + sq4(b1[rt]);
    // fragments + 12 MFMAs
    bf16x8 af[4], bfv[3];
#pragma unroll
    for (int tt = 0; tt < 4; ++tt) af[tt] = cvt8(a0[tt], a1[tt]);
#pragma unroll
    for (int rt = 0; rt < 3; ++rt) bfv[rt] = cvt8(b0[rt], b1[rt]);
#pragma unroll
    for (int tt = 0; tt < 4; ++tt)
#pragma unroll
      for (int rt = 0; rt < 3; ++rt)
        acc[tt][rt] = __builtin_amdgcn_mfma_f32_16x16x32_bf16(af[tt], bfv[rt], acc[tt][rt], 0, 0, 0);
  }

  // fold norm partials over kq groups
#pragma unroll
  for (int tt = 0; tt < 4; ++tt) {
    cnp[tt] += __shfl_xor(cnp[tt], 16);
    cnp[tt] += __shfl_xor(cnp[tt], 32);
  }
#pragma unroll
  for (int rt = 0; rt < 3; ++rt) {
    inp[rt] += __shfl_xor(inp[rt], 16);
    inp[rt] += __shfl_xor(inp[rt], 32);
  }
  if (lane < 16) {
#pragma unroll
    for (int tt = 0; tt < 4; ++tt) snc_p[w * 64 + tt * 16 + lane] = cnp[tt];
#pragma unroll
    for (int rt = 0; rt < 3; ++rt) {
      int r = rt * 16 + lane;
      if (r < RREG) sni_p[w * 48 + r] = inp[rt];
    }
  }

  // split-K combine, 2 rounds. D layout: row(t-local)=kq*4+i, col(r-local)=fm
  float* slot = pdots + (w & 3) * (TTOK * SLOTSTR);
  if (w < 4) {
#pragma unroll
    for (int tt = 0; tt < 4; ++tt)
#pragma unroll
      for (int rt = 0; rt < 3; ++rt)
#pragma unroll
        for (int i = 0; i < 4; ++i)
          slot[(tt * 16 + kq * 4 + i) * SLOTSTR + rt * 16 + fm] = acc[tt][rt][i];
  }
  __syncthreads();
  if (w >= 4) {
#pragma unroll
    for (int tt = 0; tt < 4; ++tt)
#pragma unroll
      for (int rt = 0; rt < 3; ++rt)
#pragma unroll
        for (int i = 0; i < 4; ++i) {
          int idx = (tt * 16 + kq * 4 + i) * SLOTSTR + rt * 16 + fm;
          slot[idx] += acc[tt][rt][i];
        }
  }
  __syncthreads();

  // finalize norms (column-exclusive, no races)
  if (tid < 64) {
    float s = 0.f;
#pragma unroll
    for (int w2 = 0; w2 < 8; ++w2) s += snc_p[w2 * 64 + tid];
    snc_p[tid] = sqrtf(s);
  } else if (tid < 112) {
    int r = tid - 64;
    if (r < RREG) {
      float s = 0.f;
#pragma unroll
      for (int w2 = 0; w2 < 8; ++w2) s += sni_p[w2 * 48 + r];
      sni_p[r] = sqrtf(s);
    }
  }
  __syncthreads();

  // softmax over r, one lane per token (waves 0..3 cover t=0..63)
  if (w < 4 && lane < 16) {
    const int t = w * 16 + lane;
    const float nc = snc_p[t];
    float sc[RREG];
    float mx = -1e30f;
#pragma unroll
    for (int r = 0; r < RREG; ++r) {
      float d = pdots[t * SLOTSTR + r] +
                pdots[TTOK * SLOTSTR + t * SLOTSTR + r] +
                pdots[2 * TTOK * SLOTSTR + t * SLOTSTR + r] +
                pdots[3 * TTOK * SLOTSTR + t * SLOTSTR + r];
      float v = d / fmaxf(sni_p[r] * nc, 1e-8f);
      sc[r] = v;
      mx = fmaxf(mx, v);
    }
    float sum = 0.f;
#pragma unroll
    for (int r = 0; r < RREG; ++r) {
      float ev = __expf(sc[r] - mx);
      sc[r] = ev;
      sum += ev;
    }
    const float rinv = 1.f / sum;
    unsigned short* arow = attnw + ((size_t)b * TTOK + t) * KPAD;
#pragma unroll
    for (int r0 = 0; r0 < RREG; r0 += 4) {
      ushort4 p;
      p.x = f2bf(sc[r0 + 0] * rinv);
      p.y = f2bf(sc[r0 + 1] * rinv);
      p.z = f2bf(sc[r0 + 2] * rinv);
      p.w = f2bf(sc[r0 + 3] * rinv);
      *(ushort4*)(arow + r0) = p;
    }
    ushort4 zz; zz.x = 0; zz.y = 0; zz.z = 0; zz.w = 0;
    *(ushort4*)(arow + 36) = zz;
    *(ushort4*)(arow + 40) = zz;
    *(ushort4*)(arow + 44) = zz;
  }
}

// ---------------- Kernel 2: out = attn^T(64x48) . img(48x1024) ----------------
// grid = B*4 (d-chunks of 256), block = 256 (4 waves = 4 t-tiles); no LDS, no
// barriers. ~20us ~= per-CU request floor; unchanged.
__global__ __launch_bounds__(256) void scan_out(
    const float* __restrict__ img, const unsigned short* __restrict__ attnw,
    float* __restrict__ out) {
  const int tid  = threadIdx.x;
  const int lane = tid & 63;
  const int wave = tid >> 6;        // t-tile 0..3
  const int fm   = lane & 15;
  const int kq   = lane >> 4;
  const int b    = blockIdx.x >> 2;
  const int d0   = (blockIdx.x & 3) << 8;

  const float* imgb = img + (size_t)b * RREG * DDIM;
  const unsigned short* attb = attnw + (size_t)b * TTOK * KPAD;
  float* outb = out + (size_t)b * TTOK * DDIM;

  const unsigned short* ap = attb + (wave * 16 + fm) * KPAD;
  bf16x8 zf = {0, 0, 0, 0, 0, 0, 0, 0};
  bf16x8 af0 = *(const bf16x8*)(ap + kq * 8);
  bf16x8 af1 = zf;
  if (kq < 2) af1 = *(const bf16x8*)(ap + 32 + kq * 8);

  for (int s = 0; s < 16; ++s) {
    const int d = d0 + s * 16 + fm;
    float v[8];
#pragma unroll
    for (int j = 0; j < 8; ++j) v[j] = imgb[(kq * 8 + j) * DDIM + d];
    bf16x8 bf0 = pack8(v);
    bf16x8 bf1 = zf;
    if (kq == 0) {
      float wv[8];
#pragma unroll
      for (int j = 0; j < 4; ++j) wv[j] = imgb[(32 + j) * DDIM + d];
#pragma unroll
      for (int j = 4; j < 8; ++j) wv[j] = 0.f;
      bf1 = pack8(wv);
    }
    f32x4 o = {0.f, 0.f, 0.f, 0.f};
    o = __builtin_amdgcn_mfma_f32_16x16x32_bf16(af0, bf0, o, 0, 0, 0);
    o = __builtin_amdgcn_mfma_f32_16x16x32_bf16(af1, bf1, o, 0, 0, 0);
    float* op = outb + (wave * 16 + kq * 4) * DDIM + d;
#pragma unroll
    for (int i = 0; i < 4; ++i) op[i * DDIM] = o[i];
  }
}

extern "C" void kernel_launch(void* const* d_in, const int* in_sizes, int n_in,
                              void* d_out, int out_size, void* d_ws, size_t ws_size,
                              hipStream_t stream) {
  const float* img = (const float*)d_in[0];   // (256, 36, 1024) fp32
  const float* cap = (const float*)d_in[1];   // (256, 64, 1024) fp32
  float* out = (float*)d_out;                 // (256, 64, 1024) fp32
  unsigned short* attnw = (unsigned short*)d_ws;  // attn^T bf16 [B][64][48] = 1.5 MB

  scan_attn<<<dim3(256), dim3(512), 0, stream>>>(img, cap, attnw);
  scan_out<<<dim3(1024), dim3(256), 0, stream>>>(img, attnw, out);
}

// Round 6
// 167.590 us; speedup vs baseline: 1.0595x; 1.0595x over previous
//
#include <hip/hip_runtime.h>
#include <hip/hip_bf16.h>

#define DDIM 1024
#define RREG 36
#define TTOK 64
#define KPAD 48          // attn rows padded 36->48, rows [36,48) zero
#define QSTR 1032        // LDS quad stride (4 rows x 256B + 8B pad): b64 frags 4-way max
#define BUFB (28 * QSTR) // 28896 B per chunk buffer (quads: 16 cap, 9 img, 3 zero)

typedef __attribute__((ext_vector_type(4))) float f32x4;
typedef __attribute__((ext_vector_type(8))) short bf16x8;

__device__ __forceinline__ unsigned short f2bf(float x) {
  unsigned int u = __float_as_uint(x);
  u += 0x7fffu + ((u >> 16) & 1u);
  return (unsigned short)(u >> 16);
}

__device__ __forceinline__ bf16x8 pack8(const float* v) {
  union { bf16x8 x; __hip_bfloat162 h[4]; } u;
#pragma unroll
  for (int i = 0; i < 4; ++i)
    u.h[i] = __float22bfloat162_rn(make_float2(v[2 * i], v[2 * i + 1]));
  return u.x;
}

// read 8 consecutive fp32 (32B) from LDS, optionally fold norm^2, cvt -> bf16x8
__device__ __forceinline__ bf16x8 lds_frag(const unsigned char* p, float& nsq, bool do_n) {
  float2 v0 = *(const float2*)(p);
  float2 v1 = *(const float2*)(p + 8);
  float2 v2 = *(const float2*)(p + 16);
  float2 v3 = *(const float2*)(p + 24);
  if (do_n)
    nsq += v0.x * v0.x + v0.y * v0.y + v1.x * v1.x + v1.y * v1.y +
           v2.x * v2.x + v2.y * v2.y + v3.x * v3.x + v3.y * v3.y;
  union { bf16x8 v; __hip_bfloat162 h[4]; } u;
  u.h[0] = __float22bfloat162_rn(v0);
  u.h[1] = __float22bfloat162_rn(v1);
  u.h[2] = __float22bfloat162_rn(v2);
  u.h[3] = __float22bfloat162_rn(v3);
  return u.v;
}

// ---------------- Kernel 1: dots + norms + softmax -> attn^T bf16 ----------------
// grid = B, block = 512 = 8 waves. Producer/consumer: waves 4..7 stage fp32
// cap(64r)+img(36r) K-chunks (64 floats) into double-buffered LDS via
// global_load_lds (1KB per instr, no VGPR dest -> deep MLP: the fix for the
// ~3-lines-in-flight/wave serialization that pinned every prior K1 at ~50us).
// Waves 0..3 consume: wave w = t-tile w, all 48 r, full K (no split-K).
// Raw s_barrier + s_waitcnt vmcnt(6) (never 0) keeps next chunk's DMA in
// flight across the barrier (AITER pattern; __syncthreads would drain it).
__global__ __launch_bounds__(512, 2) void scan_attn(
    const float* __restrict__ img, const float* __restrict__ cap,
    unsigned short* __restrict__ attnw) {
  __shared__ __align__(16) unsigned char smem[2 * BUFB];  // 57792 B

  const int tid  = threadIdx.x;
  const int lane = tid & 63;
  const int wave = tid >> 6;
  const int fm   = lane & 15;
  const int kq   = lane >> 4;
  const int b    = blockIdx.x;

  const float* capb = cap + (size_t)b * TTOK * DDIM;
  const float* imgb = img + (size_t)b * RREG * DDIM;

  // zero img pad quads 25..27 (rows 100..111 = img rows 36..47) in BOTH buffers
  for (int i = tid; i < 1548; i += 512) {
    int bs = (i >= 774);
    *(unsigned int*)(smem + bs * BUFB + 25 * QSTR + (size_t)(i - bs * 774) * 4) = 0u;
  }

  const bool producer = (wave >= 4);
  const int  pw = wave & 3;
  const int  lrow = lane >> 4;          // row within a quad (0..3)
  const int  lcol = (lane & 15) * 16;   // byte col within 256B row

  // issue chunk c (64 floats starting at k=c*64) into buf[c&1]
  auto issue = [&](int c) {
    unsigned char* lbuf = smem + (size_t)(c & 1) * BUFB;
    const int colb = c * 256;
    for (int qd = pw; qd < 25; qd += 4) {
      const char* g;
      if (qd < 16) g = (const char*)(capb + (size_t)(qd * 4 + lrow) * DDIM) + colb + lcol;
      else         g = (const char*)(imgb + (size_t)((qd - 16) * 4 + lrow) * DDIM) + colb + lcol;
      __builtin_amdgcn_global_load_lds(
          (const __attribute__((address_space(1))) void*)g,
          (__attribute__((address_space(3))) void*)(lbuf + (size_t)qd * QSTR),
          16, 0, 0);
    }
  };

  if (producer) {
    issue(0);
    issue(1);
    asm volatile("s_waitcnt vmcnt(6)" ::: "memory");  // chunk 0 landed
  }
  asm volatile("s_waitcnt lgkmcnt(0)" ::: "memory");  // pad zeros visible
  asm volatile("s_barrier" ::: "memory");

  f32x4 acc0 = {0.f, 0.f, 0.f, 0.f};
  f32x4 acc1 = {0.f, 0.f, 0.f, 0.f};
  f32x4 acc2 = {0.f, 0.f, 0.f, 0.f};
  float cn = 0.f, in0 = 0.f, in1 = 0.f, in2 = 0.f;

  // consumer LDS row bases (byte offsets within a buffer)
  const int arow = wave * 16 + fm;  // cap row (waves 0..3)
  const int aoff = (arow >> 2) * QSTR + (arow & 3) * 256;
  const int boff0 = 16 * QSTR + (fm >> 2) * QSTR + (fm & 3) * 256;            // img row fm
  const int boff1 = 16 * QSTR + ((16 + fm) >> 2) * QSTR + ((16 + fm) & 3) * 256;
  const int boff2 = 16 * QSTR + ((32 + fm) >> 2) * QSTR + ((32 + fm) & 3) * 256;

#pragma unroll 2
  for (int c = 0; c < 16; ++c) {
    if (!producer) {
      const unsigned char* buf = smem + (size_t)(c & 1) * BUFB;
#pragma unroll
      for (int ks = 0; ks < 2; ++ks) {
        const int ko = ks * 128 + kq * 32;
        bf16x8 af = lds_frag(buf + aoff + ko, cn, true);
        bf16x8 f0 = lds_frag(buf + boff0 + ko, in0, wave == 0);
        bf16x8 f1 = lds_frag(buf + boff1 + ko, in1, wave == 0);
        bf16x8 f2 = lds_frag(buf + boff2 + ko, in2, wave == 0);
        acc0 = __builtin_amdgcn_mfma_f32_16x16x32_bf16(af, f0, acc0, 0, 0, 0);
        acc1 = __builtin_amdgcn_mfma_f32_16x16x32_bf16(af, f1, acc1, 0, 0, 0);
        acc2 = __builtin_amdgcn_mfma_f32_16x16x32_bf16(af, f2, acc2, 0, 0, 0);
      }
    }
    asm volatile("s_waitcnt lgkmcnt(0)" ::: "memory");
    asm volatile("s_barrier" ::: "memory");   // A: buf[c&1] free for reuse
    if (producer) {
      if (c + 2 < 16) issue(c + 2);           // overwrite buf[c&1]
      asm volatile("s_waitcnt vmcnt(6)" ::: "memory");  // chunk c+1 landed
    }
    asm volatile("s_barrier" ::: "memory");   // B: chunk c+1 ready
  }

  // fold norm partials over the 4 kq lane-groups (exact fp32)
  cn  += __shfl_xor(cn, 16);  cn  += __shfl_xor(cn, 32);
  in0 += __shfl_xor(in0, 16); in0 += __shfl_xor(in0, 32);
  in1 += __shfl_xor(in1, 16); in1 += __shfl_xor(in1, 32);
  in2 += __shfl_xor(in2, 16); in2 += __shfl_xor(in2, 32);

  // dump dots + norms into buf0 region (chunk 15 lived in buf1; buf0 is dead)
  float* sdots = (float*)smem;             // [64][52]
  float* snc   = (float*)(smem + 13312);   // [64] cap-norm^2
  float* sni   = (float*)(smem + 13568);   // [48] img-norm^2
  if (!producer) {
    if (lane < 16) snc[wave * 16 + fm] = cn;
    if (wave == 0 && lane < 16) {
      sni[fm] = in0; sni[16 + fm] = in1; sni[32 + fm] = in2;
    }
    // D layout: row(t-local)=kq*4+i, col(r-local)=fm
#pragma unroll
    for (int i = 0; i < 4; ++i) {
      float* dp = sdots + (size_t)(wave * 16 + kq * 4 + i) * 52;
      dp[fm]      = acc0[i];
      dp[16 + fm] = acc1[i];
      dp[32 + fm] = acc2[i];
    }
  }
  asm volatile("s_waitcnt lgkmcnt(0)" ::: "memory");
  asm volatile("s_barrier" ::: "memory");

  // softmax over r, one lane per token (waves 0..3, lanes 0..15)
  if (wave < 4 && lane < 16) {
    const int t = wave * 16 + lane;
    const float nc = sqrtf(snc[t]);
    float sc[RREG];
    float mx = -1e30f;
#pragma unroll
    for (int r = 0; r < RREG; ++r) {
      float v = sdots[(size_t)t * 52 + r] / fmaxf(sqrtf(sni[r]) * nc, 1e-8f);
      sc[r] = v;
      mx = fmaxf(mx, v);
    }
    float sum = 0.f;
#pragma unroll
    for (int r = 0; r < RREG; ++r) {
      float ev = __expf(sc[r] - mx);
      sc[r] = ev;
      sum += ev;
    }
    const float rinv = 1.f / sum;
    unsigned short* arw = attnw + ((size_t)b * TTOK + t) * KPAD;
#pragma unroll
    for (int r0 = 0; r0 < RREG; r0 += 4) {
      ushort4 p;
      p.x = f2bf(sc[r0 + 0] * rinv);
      p.y = f2bf(sc[r0 + 1] * rinv);
      p.z = f2bf(sc[r0 + 2] * rinv);
      p.w = f2bf(sc[r0 + 3] * rinv);
      *(ushort4*)(arw + r0) = p;
    }
    ushort4 zz; zz.x = 0; zz.y = 0; zz.z = 0; zz.w = 0;
    *(ushort4*)(arw + 36) = zz;
    *(ushort4*)(arw + 40) = zz;
    *(ushort4*)(arw + 44) = zz;
  }
}

// ---------------- Kernel 2: out = attn^T(64x48) . img(48x1024) ----------------
// grid = B*8 (d-chunks of 128 -> 8 blocks/CU, 32 waves: 2x MLP vs R5's 16),
// block = 256 (4 waves = 4 t-tiles); no LDS, no barriers.
__global__ __launch_bounds__(256) void scan_out(
    const float* __restrict__ img, const unsigned short* __restrict__ attnw,
    float* __restrict__ out) {
  const int tid  = threadIdx.x;
  const int lane = tid & 63;
  const int wave = tid >> 6;        // t-tile 0..3
  const int fm   = lane & 15;
  const int kq   = lane >> 4;
  const int b    = blockIdx.x >> 3;
  const int d0   = (blockIdx.x & 7) << 7;

  const float* imgb = img + (size_t)b * RREG * DDIM;
  const unsigned short* attb = attnw + (size_t)b * TTOK * KPAD;
  float* outb = out + (size_t)b * TTOK * DDIM;

  const unsigned short* ap = attb + (wave * 16 + fm) * KPAD;
  bf16x8 zf = {0, 0, 0, 0, 0, 0, 0, 0};
  bf16x8 af0 = *(const bf16x8*)(ap + kq * 8);
  bf16x8 af1 = zf;
  if (kq < 2) af1 = *(const bf16x8*)(ap + 32 + kq * 8);

  for (int s = 0; s < 8; ++s) {
    const int d = d0 + s * 16 + fm;
    float v[8];
#pragma unroll
    for (int j = 0; j < 8; ++j) v[j] = imgb[(kq * 8 + j) * DDIM + d];
    bf16x8 bf0 = pack8(v);
    bf16x8 bf1 = zf;
    if (kq == 0) {
      float wv[8];
#pragma unroll
      for (int j = 0; j < 4; ++j) wv[j] = imgb[(32 + j) * DDIM + d];
#pragma unroll
      for (int j = 4; j < 8; ++j) wv[j] = 0.f;
      bf1 = pack8(wv);
    }
    f32x4 o = {0.f, 0.f, 0.f, 0.f};
    o = __builtin_amdgcn_mfma_f32_16x16x32_bf16(af0, bf0, o, 0, 0, 0);
    o = __builtin_amdgcn_mfma_f32_16x16x32_bf16(af1, bf1, o, 0, 0, 0);
    float* op = outb + (wave * 16 + kq * 4) * DDIM + d;
#pragma unroll
    for (int i = 0; i < 4; ++i) op[i * DDIM] = o[i];
  }
}

extern "C" void kernel_launch(void* const* d_in, const int* in_sizes, int n_in,
                              void* d_out, int out_size, void* d_ws, size_t ws_size,
                              hipStream_t stream) {
  const float* img = (const float*)d_in[0];   // (256, 36, 1024) fp32
  const float* cap = (const float*)d_in[1];   // (256, 64, 1024) fp32
  float* out = (float*)d_out;                 // (256, 64, 1024) fp32
  unsigned short* attnw = (unsigned short*)d_ws;  // attn^T bf16 [B][64][48] = 1.5 MB

  scan_attn<<<dim3(256), dim3(512), 0, stream>>>(img, cap, attnw);
  scan_out<<<dim3(2048), dim3(256), 0, stream>>>(img, attnw, out);
}